// Round 6
// baseline (1870.317 us; speedup 1.0000x reference)
//
#include <hip/hip_runtime.h>
#include <hip/hip_bf16.h>
#include <cmath>

#define S_LEN 2048
#define DMODEL 4096
#define NH 32
#define HDIM 128
#define HEAVY 256
#define RECENT 256
#define ATTN_SCALE 0.08838834764831845f  // 1/sqrt(128)
#define NEGBIG -3.0e38f
#define MB (1024ull * 1024ull)

typedef __attribute__((ext_vector_type(8))) short short8v;
typedef __attribute__((ext_vector_type(4))) short short4v;
typedef __attribute__((ext_vector_type(4))) float floatx4;

__device__ inline ushort f2bf(float x) {
  __hip_bfloat16 h = __float2bfloat16(x);
  return __builtin_bit_cast(ushort, h);
}
__device__ inline float bf2f(ushort u) {
  __hip_bfloat16 h = __builtin_bit_cast(__hip_bfloat16, u);
  return __bfloat162float(h);
}
struct Split3 {
  short a, b, c;
};
__device__ inline Split3 split3(float x) {
  Split3 o;
  ushort u1 = f2bf(x);
  float r1 = x - bf2f(u1);
  ushort u2 = f2bf(r1);
  float r2 = r1 - bf2f(u2);
  ushort u3 = f2bf(r2);
  o.a = (short)u1;
  o.b = (short)u2;
  o.c = (short)u3;
  return o;
}

// ===== elementwise 3-way split: X fp32 -> Xa,Xb,Xc bf16 =====
__global__ void split_mat(const float* __restrict__ X, short* __restrict__ Xa,
                          short* __restrict__ Xb, short* __restrict__ Xc, int n4) {
  int stride = gridDim.x * blockDim.x;
  for (int i = blockIdx.x * blockDim.x + threadIdx.x; i < n4; i += stride) {
    float4 v = reinterpret_cast<const float4*>(X)[i];
    float vv[4] = {v.x, v.y, v.z, v.w};
    short4v a, b, c;
#pragma unroll
    for (int j = 0; j < 4; j++) {
      Split3 t = split3(vv[j]);
      a[j] = t.a; b[j] = t.b; c[j] = t.c;
    }
    reinterpret_cast<short4v*>(Xa)[i] = a;
    reinterpret_cast<short4v*>(Xb)[i] = b;
    reinterpret_cast<short4v*>(Xc)[i] = c;
  }
}

// ===== 6-product GEMM from PRE-SPLIT operands: C[M][N] = A[M][K]*B[N][K]^T =====
__global__ __launch_bounds__(256) void gemm6p(
    const short* __restrict__ Aag, const short* __restrict__ Abg, const short* __restrict__ Acg,
    const short* __restrict__ Bag, const short* __restrict__ Bbg, const short* __restrict__ Bcg,
    float* __restrict__ C, int M, int N, int K) {
  __shared__ short Aa[128 * 40], Ab[128 * 40], Ac[128 * 40];
  __shared__ short Ba[128 * 40], Bb[128 * 40], Bc[128 * 40];
  const int tid = threadIdx.x;
  const int w = tid >> 6, l = tid & 63, g = l >> 4, ln = l & 15;
  const int wm = w >> 1, wn = w & 1;
  const int row0 = blockIdx.y * 128, col0 = blockIdx.x * 128;
  floatx4 acc[4][4] = {};
  for (int k0 = 0; k0 < K; k0 += 32) {
    __syncthreads();
#pragma unroll
    for (int i = 0; i < 2; i++) {
      int id = tid + i * 256;  // 512 chunks: 128 rows x 4 chunks of 8 shorts
      int r = id >> 2, c = id & 3;
      size_t ga = (size_t)(row0 + r) * K + k0 + c * 8;
      size_t gb = (size_t)(col0 + r) * K + k0 + c * 8;
      int o = r * 40 + c * 8;
      *reinterpret_cast<short8v*>(&Aa[o]) = *reinterpret_cast<const short8v*>(&Aag[ga]);
      *reinterpret_cast<short8v*>(&Ab[o]) = *reinterpret_cast<const short8v*>(&Abg[ga]);
      *reinterpret_cast<short8v*>(&Ac[o]) = *reinterpret_cast<const short8v*>(&Acg[ga]);
      *reinterpret_cast<short8v*>(&Ba[o]) = *reinterpret_cast<const short8v*>(&Bag[gb]);
      *reinterpret_cast<short8v*>(&Bb[o]) = *reinterpret_cast<const short8v*>(&Bbg[gb]);
      *reinterpret_cast<short8v*>(&Bc[o]) = *reinterpret_cast<const short8v*>(&Bcg[gb]);
    }
    __syncthreads();
#pragma unroll
    for (int i = 0; i < 4; i++) {
      int ar = (wm * 64 + i * 16 + ln) * 40 + g * 8;
      short8v a1 = *reinterpret_cast<const short8v*>(&Aa[ar]);
      short8v a2 = *reinterpret_cast<const short8v*>(&Ab[ar]);
      short8v a3 = *reinterpret_cast<const short8v*>(&Ac[ar]);
#pragma unroll
      for (int j = 0; j < 4; j++) {
        int br = (wn * 64 + j * 16 + ln) * 40 + g * 8;
        short8v b1 = *reinterpret_cast<const short8v*>(&Ba[br]);
        short8v b2 = *reinterpret_cast<const short8v*>(&Bb[br]);
        short8v b3 = *reinterpret_cast<const short8v*>(&Bc[br]);
        acc[i][j] = __builtin_amdgcn_mfma_f32_16x16x32_bf16(a1, b1, acc[i][j], 0, 0, 0);
        acc[i][j] = __builtin_amdgcn_mfma_f32_16x16x32_bf16(a1, b2, acc[i][j], 0, 0, 0);
        acc[i][j] = __builtin_amdgcn_mfma_f32_16x16x32_bf16(a2, b1, acc[i][j], 0, 0, 0);
        acc[i][j] = __builtin_amdgcn_mfma_f32_16x16x32_bf16(a1, b3, acc[i][j], 0, 0, 0);
        acc[i][j] = __builtin_amdgcn_mfma_f32_16x16x32_bf16(a2, b2, acc[i][j], 0, 0, 0);
        acc[i][j] = __builtin_amdgcn_mfma_f32_16x16x32_bf16(a3, b1, acc[i][j], 0, 0, 0);
      }
    }
  }
#pragma unroll
  for (int i = 0; i < 4; i++)
#pragma unroll
    for (int j = 0; j < 4; j++)
#pragma unroll
      for (int r = 0; r < 4; r++)
        C[(size_t)(row0 + wm * 64 + i * 16 + g * 4 + r) * N + col0 + wn * 64 + j * 16 + ln] =
            acc[i][j][r];
}

// ===== legacy 6-product GEMM with in-loop split (fallback, small ws) =====
__global__ __launch_bounds__(256) void gemm6(const float* __restrict__ A,
                                             const float* __restrict__ B,
                                             float* __restrict__ C, int M, int N, int K) {
  __shared__ short Aa[128 * 40], Ab[128 * 40], Ac[128 * 40];
  __shared__ short Ba[128 * 40], Bb[128 * 40], Bc[128 * 40];
  const int tid = threadIdx.x;
  const int w = tid >> 6, l = tid & 63, g = l >> 4, ln = l & 15;
  const int wm = w >> 1, wn = w & 1;
  const int row0 = blockIdx.y * 128, col0 = blockIdx.x * 128;
  floatx4 acc[4][4] = {};
  for (int k0 = 0; k0 < K; k0 += 32) {
    __syncthreads();
#pragma unroll
    for (int i = 0; i < 4; i++) {
      int id = tid + i * 256;
      int r = id >> 3, c4 = id & 7;
      float4 av = *reinterpret_cast<const float4*>(&A[(size_t)(row0 + r) * K + k0 + c4 * 4]);
      float4 bv = *reinterpret_cast<const float4*>(&B[(size_t)(col0 + r) * K + k0 + c4 * 4]);
      float af[4] = {av.x, av.y, av.z, av.w};
      float bf[4] = {bv.x, bv.y, bv.z, bv.w};
      short4v a1, a2, a3, b1, b2, b3;
#pragma unroll
      for (int j = 0; j < 4; j++) {
        Split3 sa = split3(af[j]);
        Split3 sb = split3(bf[j]);
        a1[j] = sa.a; a2[j] = sa.b; a3[j] = sa.c;
        b1[j] = sb.a; b2[j] = sb.b; b3[j] = sb.c;
      }
      int o = r * 40 + c4 * 4;
      *reinterpret_cast<short4v*>(&Aa[o]) = a1;
      *reinterpret_cast<short4v*>(&Ab[o]) = a2;
      *reinterpret_cast<short4v*>(&Ac[o]) = a3;
      *reinterpret_cast<short4v*>(&Ba[o]) = b1;
      *reinterpret_cast<short4v*>(&Bb[o]) = b2;
      *reinterpret_cast<short4v*>(&Bc[o]) = b3;
    }
    __syncthreads();
#pragma unroll
    for (int i = 0; i < 4; i++) {
      int ar = (wm * 64 + i * 16 + ln) * 40 + g * 8;
      short8v a1 = *reinterpret_cast<const short8v*>(&Aa[ar]);
      short8v a2 = *reinterpret_cast<const short8v*>(&Ab[ar]);
      short8v a3 = *reinterpret_cast<const short8v*>(&Ac[ar]);
#pragma unroll
      for (int j = 0; j < 4; j++) {
        int br = (wn * 64 + j * 16 + ln) * 40 + g * 8;
        short8v b1 = *reinterpret_cast<const short8v*>(&Ba[br]);
        short8v b2 = *reinterpret_cast<const short8v*>(&Bb[br]);
        short8v b3 = *reinterpret_cast<const short8v*>(&Bc[br]);
        acc[i][j] = __builtin_amdgcn_mfma_f32_16x16x32_bf16(a1, b1, acc[i][j], 0, 0, 0);
        acc[i][j] = __builtin_amdgcn_mfma_f32_16x16x32_bf16(a1, b2, acc[i][j], 0, 0, 0);
        acc[i][j] = __builtin_amdgcn_mfma_f32_16x16x32_bf16(a2, b1, acc[i][j], 0, 0, 0);
        acc[i][j] = __builtin_amdgcn_mfma_f32_16x16x32_bf16(a1, b3, acc[i][j], 0, 0, 0);
        acc[i][j] = __builtin_amdgcn_mfma_f32_16x16x32_bf16(a2, b2, acc[i][j], 0, 0, 0);
        acc[i][j] = __builtin_amdgcn_mfma_f32_16x16x32_bf16(a3, b1, acc[i][j], 0, 0, 0);
      }
    }
  }
#pragma unroll
  for (int i = 0; i < 4; i++)
#pragma unroll
    for (int j = 0; j < 4; j++)
#pragma unroll
      for (int r = 0; r < 4; r++)
        C[(size_t)(row0 + wm * 64 + i * 16 + g * 4 + r) * N + col0 + wn * 64 + j * 16 + ln] =
            acc[i][j][r];
}

// ===== plain bf16 GEMM, fp32 out (Wo) =====
__global__ __launch_bounds__(256) void gemm_bf1(const float* __restrict__ A,
                                                const float* __restrict__ B,
                                                float* __restrict__ C, int M, int N, int K) {
  __shared__ short Ah[128 * 40];
  __shared__ short Bh[128 * 40];
  const int tid = threadIdx.x;
  const int w = tid >> 6, l = tid & 63, g = l >> 4, ln = l & 15;
  const int wm = w >> 1, wn = w & 1;
  const int row0 = blockIdx.y * 128, col0 = blockIdx.x * 128;
  floatx4 acc[4][4] = {};
  for (int k0 = 0; k0 < K; k0 += 32) {
    __syncthreads();
#pragma unroll
    for (int i = 0; i < 4; i++) {
      int id = tid + i * 256;
      int r = id >> 3, c4 = id & 7;
      float4 av = *reinterpret_cast<const float4*>(&A[(size_t)(row0 + r) * K + k0 + c4 * 4]);
      float4 bv = *reinterpret_cast<const float4*>(&B[(size_t)(col0 + r) * K + k0 + c4 * 4]);
      short4v ah, bh;
      ah[0] = (short)f2bf(av.x); ah[1] = (short)f2bf(av.y);
      ah[2] = (short)f2bf(av.z); ah[3] = (short)f2bf(av.w);
      bh[0] = (short)f2bf(bv.x); bh[1] = (short)f2bf(bv.y);
      bh[2] = (short)f2bf(bv.z); bh[3] = (short)f2bf(bv.w);
      *reinterpret_cast<short4v*>(&Ah[r * 40 + c4 * 4]) = ah;
      *reinterpret_cast<short4v*>(&Bh[r * 40 + c4 * 4]) = bh;
    }
    __syncthreads();
#pragma unroll
    for (int i = 0; i < 4; i++) {
      short8v a = *reinterpret_cast<const short8v*>(&Ah[(wm * 64 + i * 16 + ln) * 40 + g * 8]);
#pragma unroll
      for (int j = 0; j < 4; j++) {
        short8v b = *reinterpret_cast<const short8v*>(&Bh[(wn * 64 + j * 16 + ln) * 40 + g * 8]);
        acc[i][j] = __builtin_amdgcn_mfma_f32_16x16x32_bf16(a, b, acc[i][j], 0, 0, 0);
      }
    }
  }
#pragma unroll
  for (int i = 0; i < 4; i++)
#pragma unroll
    for (int j = 0; j < 4; j++)
#pragma unroll
      for (int r = 0; r < 4; r++)
        C[(size_t)(row0 + wm * 64 + i * 16 + g * 4 + r) * N + col0 + wn * 64 + j * 16 + ln] =
            acc[i][j][r];
}

// ===== bf16 GEMM, transposed bf16 out. AK==1: A already bf16 (Ha) =====
template <int AK>
__global__ __launch_bounds__(256) void gemm_vbt(const void* __restrict__ Av,
                                                const float* __restrict__ B,
                                                ushort* __restrict__ Vt, int M, int N, int K) {
  __shared__ short Ah[128 * 40];
  __shared__ short Bh[128 * 40];
  const int tid = threadIdx.x;
  const int w = tid >> 6, l = tid & 63, g = l >> 4, ln = l & 15;
  const int wm = w >> 1, wn = w & 1;
  const int row0 = blockIdx.y * 128, col0 = blockIdx.x * 128;
  floatx4 acc[4][4] = {};
  for (int k0 = 0; k0 < K; k0 += 32) {
    __syncthreads();
    if (AK) {
      const short* Ab = (const short*)Av;
#pragma unroll
      for (int i = 0; i < 2; i++) {
        int id = tid + i * 256;
        int r = id >> 2, c = id & 3;
        *reinterpret_cast<short8v*>(&Ah[r * 40 + c * 8]) =
            *reinterpret_cast<const short8v*>(&Ab[(size_t)(row0 + r) * K + k0 + c * 8]);
      }
    }
#pragma unroll
    for (int i = 0; i < 4; i++) {
      int id = tid + i * 256;
      int r = id >> 3, c4 = id & 7;
      if (!AK) {
        const float* Af = (const float*)Av;
        float4 av = *reinterpret_cast<const float4*>(&Af[(size_t)(row0 + r) * K + k0 + c4 * 4]);
        short4v ah;
        ah[0] = (short)f2bf(av.x); ah[1] = (short)f2bf(av.y);
        ah[2] = (short)f2bf(av.z); ah[3] = (short)f2bf(av.w);
        *reinterpret_cast<short4v*>(&Ah[r * 40 + c4 * 4]) = ah;
      }
      float4 bv = *reinterpret_cast<const float4*>(&B[(size_t)(col0 + r) * K + k0 + c4 * 4]);
      short4v bh;
      bh[0] = (short)f2bf(bv.x); bh[1] = (short)f2bf(bv.y);
      bh[2] = (short)f2bf(bv.z); bh[3] = (short)f2bf(bv.w);
      *reinterpret_cast<short4v*>(&Bh[r * 40 + c4 * 4]) = bh;
    }
    __syncthreads();
#pragma unroll
    for (int i = 0; i < 4; i++) {
      short8v a = *reinterpret_cast<const short8v*>(&Ah[(wm * 64 + i * 16 + ln) * 40 + g * 8]);
#pragma unroll
      for (int j = 0; j < 4; j++) {
        short8v b = *reinterpret_cast<const short8v*>(&Bh[(wn * 64 + j * 16 + ln) * 40 + g * 8]);
        acc[i][j] = __builtin_amdgcn_mfma_f32_16x16x32_bf16(a, b, acc[i][j], 0, 0, 0);
      }
    }
  }
#pragma unroll
  for (int i = 0; i < 4; i++)
#pragma unroll
    for (int j = 0; j < 4; j++) {
      short4v o;
#pragma unroll
      for (int r = 0; r < 4; r++) o[r] = (short)f2bf(acc[i][j][r]);
      size_t n = col0 + wn * 64 + j * 16 + ln;
      size_t m0 = row0 + wm * 64 + i * 16 + g * 4;
      *reinterpret_cast<short4v*>(&Vt[n * M + m0]) = o;
    }
}

// ===== RoPE + 3-way split of Q,K =====
__global__ void rope_convert(const float* __restrict__ Q, const float* __restrict__ K,
                             const int* __restrict__ pos, short* __restrict__ Qa,
                             short* __restrict__ Qb, short* __restrict__ Qc,
                             short* __restrict__ Ka, short* __restrict__ Kb,
                             short* __restrict__ Kc) {
  int idx = blockIdx.x * blockDim.x + threadIdx.x;
  if (idx >= S_LEN * 64) return;
  int d = idx & 63;
  int r = idx >> 6;
  float p = (float)pos[r];
  float invf = (float)pow(10000.0, -(double)(2 * d) / 128.0);
  float ang = p * invf;
  float c = cosf(ang), s = sinf(ang);
  for (int h = 0; h < NH; h++) {
    size_t base = (size_t)r * DMODEL + h * HDIM + d;
    float q1 = Q[base], q2 = Q[base + 64];
    float k1 = K[base], k2 = K[base + 64];
    float qa = q1 * c - q2 * s, qb = q2 * c + q1 * s;
    float ka = k1 * c - k2 * s, kb = k2 * c + k1 * s;
    Split3 t;
    t = split3(qa); Qa[base] = t.a; Qb[base] = t.b; Qc[base] = t.c;
    t = split3(qb); Qa[base + 64] = t.a; Qb[base + 64] = t.b; Qc[base + 64] = t.c;
    t = split3(ka); Ka[base] = t.a; Kb[base] = t.b; Kc[base] = t.c;
    t = split3(kb); Ka[base + 64] = t.a; Kb[base + 64] = t.b; Kc[base + 64] = t.c;
  }
}

// ===== fused flash attention: paired q-blocks, KVB=32, dbuf, 6-acc MFMA ILP =====
#define KVB 32
#define KTILE_SH (KVB * 128)

__device__ __forceinline__ floatx4 qk6_tile(const short* KaS, const short* KbS,
                                            const short* KcS, const short8v q1[4],
                                            const short8v q2[4], const short8v q3[4],
                                            int krow, int g) {
  floatx4 cA = {}, cB = {}, cC = {}, cD = {}, cE = {}, cF = {};
#pragma unroll
  for (int dc = 0; dc < 4; dc++) {
    int didx = krow * 128 + ((dc * 32 + g * 8) ^ ((krow & 7) << 3));
    short8v k1 = *reinterpret_cast<const short8v*>(&KaS[didx]);
    short8v k2 = *reinterpret_cast<const short8v*>(&KbS[didx]);
    short8v k3 = *reinterpret_cast<const short8v*>(&KcS[didx]);
    cA = __builtin_amdgcn_mfma_f32_16x16x32_bf16(q1[dc], k1, cA, 0, 0, 0);
    cB = __builtin_amdgcn_mfma_f32_16x16x32_bf16(q1[dc], k2, cB, 0, 0, 0);
    cC = __builtin_amdgcn_mfma_f32_16x16x32_bf16(q2[dc], k1, cC, 0, 0, 0);
    cD = __builtin_amdgcn_mfma_f32_16x16x32_bf16(q1[dc], k3, cD, 0, 0, 0);
    cE = __builtin_amdgcn_mfma_f32_16x16x32_bf16(q2[dc], k2, cE, 0, 0, 0);
    cF = __builtin_amdgcn_mfma_f32_16x16x32_bf16(q3[dc], k1, cF, 0, 0, 0);
  }
  return ((cA + cB) + (cC + cD)) + (cE + cF);
}

__device__ __forceinline__ void stage_load(const short* __restrict__ Ka,
                                           const short* __restrict__ Kb,
                                           const short* __restrict__ Kc, int k0, int h, int tid,
                                           short8v sA[2], short8v sB[2], short8v sC[2]) {
#pragma unroll
  for (int i = 0; i < 2; i++) {
    int id = tid + i * 256;
    int r = id >> 4, c = id & 15;
    size_t goff = (size_t)(k0 + r) * DMODEL + h * HDIM + c * 8;
    sA[i] = *reinterpret_cast<const short8v*>(&Ka[goff]);
    sB[i] = *reinterpret_cast<const short8v*>(&Kb[goff]);
    sC[i] = *reinterpret_cast<const short8v*>(&Kc[goff]);
  }
}

__device__ __forceinline__ void stage_store(short* KaS, short* KbS, short* KcS, int tid,
                                            const short8v sA[2], const short8v sB[2],
                                            const short8v sC[2]) {
#pragma unroll
  for (int i = 0; i < 2; i++) {
    int id = tid + i * 256;
    int r = id >> 4, c = id & 15;
    int didx = r * 128 + ((c * 8) ^ ((r & 7) << 3));
    *reinterpret_cast<short8v*>(&KaS[didx]) = sA[i];
    *reinterpret_cast<short8v*>(&KbS[didx]) = sB[i];
    *reinterpret_cast<short8v*>(&KcS[didx]) = sC[i];
  }
}

__device__ void process_qblock(int qb, int h, const short* __restrict__ Qa,
                               const short* __restrict__ Qb, const short* __restrict__ Qc,
                               const short* __restrict__ Ka, const short* __restrict__ Kb,
                               const short* __restrict__ Kc, const ushort* __restrict__ Vt,
                               float* __restrict__ AO, float* __restrict__ sp4, short* KS0,
                               short* Ps, int tid, int w, int g, int ln) {
  const int q0 = qb * 64;
  const int qrow = q0 + w * 16 + ln;
  short8v q1[4], q2[4], q3[4];
#pragma unroll
  for (int dc = 0; dc < 4; dc++) {
    size_t off = (size_t)qrow * DMODEL + h * HDIM + dc * 32 + g * 8;
    q1[dc] = *reinterpret_cast<const short8v*>(&Qa[off]);
    q2[dc] = *reinterpret_cast<const short8v*>(&Qb[off]);
    q3[dc] = *reinterpret_cast<const short8v*>(&Qc[off]);
  }
  float m_r[4], l_r[4];
#pragma unroll
  for (int r = 0; r < 4; r++) { m_r[r] = NEGBIG; l_r[r] = 0.f; }
  const int nkt = 2 * qb + 2;
  short8v sA[2], sB[2], sC[2];

  // ---- pass 1: exact per-row max & sum ----
  stage_load(Ka, Kb, Kc, 0, h, tid, sA, sB, sC);
  stage_store(KS0 + 0, KS0 + KTILE_SH, KS0 + 2 * KTILE_SH, tid, sA, sB, sC);
  __syncthreads();
  for (int t = 0; t < nkt; t++) {
    const int k0 = t * KVB;
    const int cur = t & 1, nxt = cur ^ 1;
    const bool pre = (t + 1 < nkt);
    if (pre) stage_load(Ka, Kb, Kc, k0 + KVB, h, tid, sA, sB, sC);
    short* KaS = KS0 + cur * 3 * KTILE_SH;
    float sv[2][4];
#pragma unroll
    for (int ct = 0; ct < 2; ct++) {
      floatx4 sacc = qk6_tile(KaS, KaS + KTILE_SH, KaS + 2 * KTILE_SH, q1, q2, q3, ct * 16 + ln, g);
#pragma unroll
      for (int r = 0; r < 4; r++) {
        float s = sacc[r] * ATTN_SCALE;
        int key = k0 + ct * 16 + ln;
        int qq = q0 + w * 16 + g * 4 + r;
        sv[ct][r] = (key <= qq) ? s : NEGBIG;
      }
    }
#pragma unroll
    for (int r = 0; r < 4; r++) {
      float tmax = fmaxf(sv[0][r], sv[1][r]);
      tmax = fmaxf(tmax, __shfl_xor(tmax, 1));
      tmax = fmaxf(tmax, __shfl_xor(tmax, 2));
      tmax = fmaxf(tmax, __shfl_xor(tmax, 4));
      tmax = fmaxf(tmax, __shfl_xor(tmax, 8));
      float mnew = fmaxf(m_r[r], tmax);
      float ssum = __expf(sv[0][r] - mnew) + __expf(sv[1][r] - mnew);
      ssum += __shfl_xor(ssum, 1);
      ssum += __shfl_xor(ssum, 2);
      ssum += __shfl_xor(ssum, 4);
      ssum += __shfl_xor(ssum, 8);
      l_r[r] = l_r[r] * __expf(m_r[r] - mnew) + ssum;
      m_r[r] = mnew;
    }
    if (pre) {
      short* KaN = KS0 + nxt * 3 * KTILE_SH;
      stage_store(KaN, KaN + KTILE_SH, KaN + 2 * KTILE_SH, tid, sA, sB, sC);
    }
    __syncthreads();
  }
  float inv_l[4];
#pragma unroll
  for (int r = 0; r < 4; r++) inv_l[r] = 1.0f / l_r[r];

  // ---- pass 2: normalized p, colsums, PV ----
  floatx4 o[8] = {};
  stage_load(Ka, Kb, Kc, 0, h, tid, sA, sB, sC);
  stage_store(KS0 + 0, KS0 + KTILE_SH, KS0 + 2 * KTILE_SH, tid, sA, sB, sC);
  __syncthreads();
  for (int t = 0; t < nkt; t++) {
    const int k0 = t * KVB;
    const int cur = t & 1, nxt = cur ^ 1;
    const bool pre = (t + 1 < nkt);
    if (pre) stage_load(Ka, Kb, Kc, k0 + KVB, h, tid, sA, sB, sC);
    short* KaS = KS0 + cur * 3 * KTILE_SH;
    float pv[2][4];
#pragma unroll
    for (int ct = 0; ct < 2; ct++) {
      floatx4 sacc = qk6_tile(KaS, KaS + KTILE_SH, KaS + 2 * KTILE_SH, q1, q2, q3, ct * 16 + ln, g);
#pragma unroll
      for (int r = 0; r < 4; r++) {
        float s = sacc[r] * ATTN_SCALE;
        int key = k0 + ct * 16 + ln;
        int qq = q0 + w * 16 + g * 4 + r;
        s = (key <= qq) ? s : NEGBIG;
        pv[ct][r] = __expf(s - m_r[r]) * inv_l[r];
      }
    }
#pragma unroll
    for (int ct = 0; ct < 2; ct++) {
      float c2 = pv[ct][0] + pv[ct][1] + pv[ct][2] + pv[ct][3];
      c2 += __shfl_xor(c2, 16);
      c2 += __shfl_xor(c2, 32);
      if (g == 0) sp4[((size_t)(qb * 4 + w) * NH + h) * S_LEN + k0 + ct * 16 + ln] = c2;
    }
#pragma unroll
    for (int ct = 0; ct < 2; ct++)
#pragma unroll
      for (int r = 0; r < 4; r++) {
        int prow = g * 4 + r, pcol = ct * 16 + ln;
        Ps[w * 512 + prow * 32 + (pcol ^ (((prow >> 1) & 1) << 4))] = (short)f2bf(pv[ct][r]);
      }
    short8v pa = *reinterpret_cast<const short8v*>(
        &Ps[w * 512 + ln * 32 + ((g * 8) ^ (((ln >> 1) & 1) << 4))]);
#pragma unroll
    for (int ctd = 0; ctd < 8; ctd++) {
      size_t voff = ((size_t)h * HDIM + ctd * 16 + ln) * S_LEN + k0 + g * 8;
      short8v vb = *reinterpret_cast<const short8v*>(&Vt[voff]);
      o[ctd] = __builtin_amdgcn_mfma_f32_16x16x32_bf16(pa, vb, o[ctd], 0, 0, 0);
    }
    if (pre) {
      short* KaN = KS0 + nxt * 3 * KTILE_SH;
      stage_store(KaN, KaN + KTILE_SH, KaN + 2 * KTILE_SH, tid, sA, sB, sC);
    }
    __syncthreads();
  }
#pragma unroll
  for (int ctd = 0; ctd < 8; ctd++)
#pragma unroll
    for (int r = 0; r < 4; r++)
      AO[(size_t)(q0 + w * 16 + g * 4 + r) * DMODEL + h * HDIM + ctd * 16 + ln] = o[ctd][r];
}

__global__ __launch_bounds__(256) void attn_fused(
    const short* __restrict__ Qa, const short* __restrict__ Qb, const short* __restrict__ Qc,
    const short* __restrict__ Ka, const short* __restrict__ Kb, const short* __restrict__ Kc,
    const ushort* __restrict__ Vt, float* __restrict__ AO, float* __restrict__ sp4) {
  __shared__ short KS[2 * 3 * KTILE_SH];
  __shared__ short Ps[4 * 512];
  const int bid = blockIdx.x;
  const int pid = bid >> 5, h = bid & 31;
  const int tid = threadIdx.x;
  const int w = tid >> 6, l = tid & 63, g = l >> 4, ln = l & 15;
  (void)l;
  process_qblock(31 - pid, h, Qa, Qb, Qc, Ka, Kb, Kc, Vt, AO, sp4, KS, Ps, tid, w, g, ln);
  process_qblock(pid, h, Qa, Qb, Qc, Ka, Kb, Kc, Vt, AO, sp4, KS, Ps, tid, w, g, ln);
}

// ---------------- reduce column-sum partials (128 per (h,k)) ----------------
__global__ void reduce_scores(const float* __restrict__ sp4, float* __restrict__ scores) {
  int idx = blockIdx.x * blockDim.x + threadIdx.x;
  if (idx >= NH * S_LEN) return;
  int h = idx >> 11, k = idx & 2047;
  float s = 0.f;
  for (int j = 0; j < 128; j++) s += sp4[((size_t)j * NH + h) * S_LEN + k];
  scores[idx] = s;
}

// ---------------- per-head exact top-256 + mask + previous_scores ----------------
__global__ __launch_bounds__(256) void topk_mask_kernel(const float* __restrict__ scores,
                                                        float* __restrict__ out_mask,
                                                        float* __restrict__ prev_scores) {
  const int h = blockIdx.x;
  __shared__ unsigned sb[S_LEN - RECENT];
  __shared__ int cnt_sh;
  const int NSEL = S_LEN - RECENT;
  const int tid = threadIdx.x;
  const float* sc = scores + (size_t)h * S_LEN;
  for (int i = tid; i < NSEL; i += 256) sb[i] = __float_as_uint(sc[i]);
  __syncthreads();
  unsigned prefix = 0u;
  for (int b = 31; b >= 0; b--) {
    unsigned cand = prefix | (1u << b);
    if (tid == 0) cnt_sh = 0;
    __syncthreads();
    int c = 0;
    for (int i = tid; i < NSEL; i += 256) c += (sb[i] >= cand) ? 1 : 0;
    atomicAdd(&cnt_sh, c);
    __syncthreads();
    if (cnt_sh >= HEAVY) prefix = cand;
    __syncthreads();
  }
  if (tid == 0) cnt_sh = 0;
  __syncthreads();
  int c = 0;
  for (int i = tid; i < NSEL; i += 256) c += (sb[i] > prefix) ? 1 : 0;
  atomicAdd(&cnt_sh, c);
  __syncthreads();
  const int c1 = cnt_sh;
  float* mrow = out_mask + (size_t)h * (S_LEN + 1);
  float* prow = prev_scores + (size_t)h * S_LEN;
  for (int j = NSEL + tid; j < S_LEN + 1; j += 256) mrow[j] = 1.0f;
  for (int k = NSEL + tid; k < S_LEN; k += 256) prow[k] = sc[k];
  for (int i = tid; i < NSEL; i += 256) {
    bool sel = sb[i] > prefix;
    mrow[i] = sel ? 1.f : 0.f;
    prow[i] = sel ? sc[i] : 0.f;
  }
  __syncthreads();
  if (tid == 0) {
    int need = HEAVY - c1;
    for (int i = 0; i < NSEL && need > 0; i++) {
      if (sb[i] == prefix) { mrow[i] = 1.f; prow[i] = sc[i]; need--; }
    }
  }
}

extern "C" void kernel_launch(void* const* d_in, const int* in_sizes, int n_in,
                              void* d_out, int out_size, void* d_ws, size_t ws_size,
                              hipStream_t stream) {
  const float* hidden = (const float*)d_in[0];
  const int* pos = (const int*)d_in[2];
  const float* Wq = (const float*)d_in[3];
  const float* Wk = (const float*)d_in[4];
  const float* Wv = (const float*)d_in[5];
  const float* Wo = (const float*)d_in[6];

  float* out0 = (float*)d_out;
  float* out_mask = out0 + (size_t)S_LEN * DMODEL;
  float* prev_scores = out_mask + (size_t)NH * (S_LEN + 1);

  char* ws = (char*)d_ws;
  float* Qf = (float*)(ws + 0 * MB);
  float* Kf = (float*)(ws + 32 * MB);
  ushort* Vt = (ushort*)(ws + 64 * MB);
  short* Qa = (short*)(ws + 80 * MB);
  short* Qb = (short*)(ws + 96 * MB);
  short* Qc = (short*)(ws + 112 * MB);
  short* Ka = (short*)(ws + 128 * MB);
  short* Kb = (short*)(ws + 144 * MB);
  short* Kc = (short*)(ws + 160 * MB);
  float* AO = Qf;
  float* sp4 = Kf;
  float* scores = (float*)(ws + 64 * MB);  // Vt dead after attn

  dim3 gg(DMODEL / 128, S_LEN / 128);
  const bool big = ws_size >= 224 * MB;
  if (big) {
    // W-split scratch overlays the (later) Qa..Kc region 80..176MB
    short* Wsa = (short*)(ws + 80 * MB);
    short* Wsb = (short*)(ws + 112 * MB);
    short* Wsc = (short*)(ws + 144 * MB);
    short* Ha = (short*)(ws + 176 * MB);
    short* Hb = (short*)(ws + 192 * MB);
    short* Hc = (short*)(ws + 208 * MB);
    split_mat<<<2048, 256, 0, stream>>>(hidden, Ha, Hb, Hc, S_LEN * DMODEL / 4);
    split_mat<<<2048, 256, 0, stream>>>(Wq, Wsa, Wsb, Wsc, DMODEL * DMODEL / 4);
    gemm6p<<<gg, 256, 0, stream>>>(Ha, Hb, Hc, Wsa, Wsb, Wsc, Qf, S_LEN, DMODEL, DMODEL);
    split_mat<<<2048, 256, 0, stream>>>(Wk, Wsa, Wsb, Wsc, DMODEL * DMODEL / 4);
    gemm6p<<<gg, 256, 0, stream>>>(Ha, Hb, Hc, Wsa, Wsb, Wsc, Kf, S_LEN, DMODEL, DMODEL);
    gemm_vbt<1><<<gg, 256, 0, stream>>>(Ha, Wv, Vt, S_LEN, DMODEL, DMODEL);
  } else {
    gemm6<<<gg, 256, 0, stream>>>(hidden, Wq, Qf, S_LEN, DMODEL, DMODEL);
    gemm6<<<gg, 256, 0, stream>>>(hidden, Wk, Kf, S_LEN, DMODEL, DMODEL);
    gemm_vbt<0><<<gg, 256, 0, stream>>>(hidden, Wv, Vt, S_LEN, DMODEL, DMODEL);
  }

  int rope_total = S_LEN * 64;
  rope_convert<<<(rope_total + 255) / 256, 256, 0, stream>>>(Qf, Kf, pos, Qa, Qb, Qc, Ka, Kb, Kc);

  hipError_t _e = hipMemsetAsync(sp4, 0, (size_t)128 * NH * S_LEN * sizeof(float), stream);
  (void)_e;
  attn_fused<<<512, 256, 0, stream>>>(Qa, Qb, Qc, Ka, Kb, Kc, Vt, AO, sp4);

  reduce_scores<<<(NH * S_LEN + 255) / 256, 256, 0, stream>>>(sp4, scores);
  topk_mask_kernel<<<NH, 256, 0, stream>>>(scores, out_mask, prev_scores);

  gemm_bf1<<<gg, 256, 0, stream>>>(AO, Wo, out0, S_LEN, DMODEL, DMODEL);
}

// Round 7
// 1593.745 us; speedup vs baseline: 1.1735x; 1.1735x over previous
//
#include <hip/hip_runtime.h>
#include <hip/hip_bf16.h>
#include <cmath>

#define S_LEN 2048
#define DMODEL 4096
#define NH 32
#define HDIM 128
#define HEAVY 256
#define RECENT 256
#define ATTN_SCALE 0.08838834764831845f  // 1/sqrt(128)
#define NEGBIG -3.0e38f
#define MB (1024ull * 1024ull)

typedef __attribute__((ext_vector_type(8))) short short8v;
typedef __attribute__((ext_vector_type(4))) short short4v;
typedef __attribute__((ext_vector_type(4))) float floatx4;

__device__ inline ushort f2bf(float x) {
  __hip_bfloat16 h = __float2bfloat16(x);
  return __builtin_bit_cast(ushort, h);
}
struct Split3 {
  short a, b, c;
};
// Truncation split: x == a+b+c EXACTLY (24 mantissa bits = 3x8). ~6 VALU.
__device__ inline Split3 split3(float x) {
  unsigned u = __float_as_uint(x);
  unsigned u1 = u & 0xFFFF0000u;
  float r1 = x - __uint_as_float(u1);
  unsigned u2 = __float_as_uint(r1) & 0xFFFF0000u;
  float r2 = r1 - __uint_as_float(u2);
  unsigned u3 = __float_as_uint(r2);  // low 16 bits are zero (<=8 significant bits left)
  Split3 o;
  o.a = (short)(u1 >> 16);
  o.b = (short)(u2 >> 16);
  o.c = (short)(u3 >> 16);
  return o;
}

__device__ __forceinline__ void gl_lds16(const short* gsrc, short* ldst) {
  __builtin_amdgcn_global_load_lds((const __attribute__((address_space(1))) void*)gsrc,
                                   (__attribute__((address_space(3))) void*)ldst, 16, 0, 0);
}

// ===== elementwise 3-way split: X fp32 -> Xa,Xb,Xc bf16 =====
__global__ void split_mat(const float* __restrict__ X, short* __restrict__ Xa,
                          short* __restrict__ Xb, short* __restrict__ Xc, int n4) {
  int stride = gridDim.x * blockDim.x;
  for (int i = blockIdx.x * blockDim.x + threadIdx.x; i < n4; i += stride) {
    float4 v = reinterpret_cast<const float4*>(X)[i];
    float vv[4] = {v.x, v.y, v.z, v.w};
    short4v a, b, c;
#pragma unroll
    for (int j = 0; j < 4; j++) {
      Split3 t = split3(vv[j]);
      a[j] = t.a; b[j] = t.b; c[j] = t.c;
    }
    reinterpret_cast<short4v*>(Xa)[i] = a;
    reinterpret_cast<short4v*>(Xb)[i] = b;
    reinterpret_cast<short4v*>(Xc)[i] = c;
  }
}

// ===== 6-product GEMM, A pre-split, B split in-kernel: C = A[M][K]*B[N][K]^T =====
__global__ __launch_bounds__(256) void gemm6h(const short* __restrict__ Aag,
                                              const short* __restrict__ Abg,
                                              const short* __restrict__ Acg,
                                              const float* __restrict__ B,
                                              float* __restrict__ C, int M, int N, int K) {
  __shared__ short Aa[128 * 40], Ab[128 * 40], Ac[128 * 40];
  __shared__ short Ba[128 * 40], Bb[128 * 40], Bc[128 * 40];
  const int tid = threadIdx.x;
  const int w = tid >> 6, l = tid & 63, g = l >> 4, ln = l & 15;
  const int wm = w >> 1, wn = w & 1;
  const int row0 = blockIdx.y * 128, col0 = blockIdx.x * 128;
  floatx4 acc[4][4] = {};
  for (int k0 = 0; k0 < K; k0 += 32) {
    __syncthreads();
#pragma unroll
    for (int i = 0; i < 2; i++) {  // A: 512 chunks of 8 shorts
      int id = tid + i * 256;
      int r = id >> 2, c = id & 3;
      size_t ga = (size_t)(row0 + r) * K + k0 + c * 8;
      int o = r * 40 + c * 8;
      *reinterpret_cast<short8v*>(&Aa[o]) = *reinterpret_cast<const short8v*>(&Aag[ga]);
      *reinterpret_cast<short8v*>(&Ab[o]) = *reinterpret_cast<const short8v*>(&Abg[ga]);
      *reinterpret_cast<short8v*>(&Ac[o]) = *reinterpret_cast<const short8v*>(&Acg[ga]);
    }
#pragma unroll
    for (int i = 0; i < 4; i++) {  // B: 1024 float4, split in-kernel
      int id = tid + i * 256;
      int r = id >> 3, c4 = id & 7;
      float4 bv = *reinterpret_cast<const float4*>(&B[(size_t)(col0 + r) * K + k0 + c4 * 4]);
      float bf[4] = {bv.x, bv.y, bv.z, bv.w};
      short4v b1, b2, b3;
#pragma unroll
      for (int j = 0; j < 4; j++) {
        Split3 t = split3(bf[j]);
        b1[j] = t.a; b2[j] = t.b; b3[j] = t.c;
      }
      int o = r * 40 + c4 * 4;
      *reinterpret_cast<short4v*>(&Ba[o]) = b1;
      *reinterpret_cast<short4v*>(&Bb[o]) = b2;
      *reinterpret_cast<short4v*>(&Bc[o]) = b3;
    }
    __syncthreads();
#pragma unroll
    for (int i = 0; i < 4; i++) {
      int ar = (wm * 64 + i * 16 + ln) * 40 + g * 8;
      short8v a1 = *reinterpret_cast<const short8v*>(&Aa[ar]);
      short8v a2 = *reinterpret_cast<const short8v*>(&Ab[ar]);
      short8v a3 = *reinterpret_cast<const short8v*>(&Ac[ar]);
#pragma unroll
      for (int j = 0; j < 4; j++) {
        int br = (wn * 64 + j * 16 + ln) * 40 + g * 8;
        short8v b1 = *reinterpret_cast<const short8v*>(&Ba[br]);
        short8v b2 = *reinterpret_cast<const short8v*>(&Bb[br]);
        short8v b3 = *reinterpret_cast<const short8v*>(&Bc[br]);
        acc[i][j] = __builtin_amdgcn_mfma_f32_16x16x32_bf16(a1, b1, acc[i][j], 0, 0, 0);
        acc[i][j] = __builtin_amdgcn_mfma_f32_16x16x32_bf16(a1, b2, acc[i][j], 0, 0, 0);
        acc[i][j] = __builtin_amdgcn_mfma_f32_16x16x32_bf16(a2, b1, acc[i][j], 0, 0, 0);
        acc[i][j] = __builtin_amdgcn_mfma_f32_16x16x32_bf16(a1, b3, acc[i][j], 0, 0, 0);
        acc[i][j] = __builtin_amdgcn_mfma_f32_16x16x32_bf16(a2, b2, acc[i][j], 0, 0, 0);
        acc[i][j] = __builtin_amdgcn_mfma_f32_16x16x32_bf16(a3, b1, acc[i][j], 0, 0, 0);
      }
    }
  }
#pragma unroll
  for (int i = 0; i < 4; i++)
#pragma unroll
    for (int j = 0; j < 4; j++)
#pragma unroll
      for (int r = 0; r < 4; r++)
        C[(size_t)(row0 + wm * 64 + i * 16 + g * 4 + r) * N + col0 + wn * 64 + j * 16 + ln] =
            acc[i][j][r];
}

// ===== plain bf16 GEMM, fp32 out (Wo) =====
__global__ __launch_bounds__(256) void gemm_bf1(const float* __restrict__ A,
                                                const float* __restrict__ B,
                                                float* __restrict__ C, int M, int N, int K) {
  __shared__ short Ah[128 * 40];
  __shared__ short Bh[128 * 40];
  const int tid = threadIdx.x;
  const int w = tid >> 6, l = tid & 63, g = l >> 4, ln = l & 15;
  const int wm = w >> 1, wn = w & 1;
  const int row0 = blockIdx.y * 128, col0 = blockIdx.x * 128;
  floatx4 acc[4][4] = {};
  for (int k0 = 0; k0 < K; k0 += 32) {
    __syncthreads();
#pragma unroll
    for (int i = 0; i < 4; i++) {
      int id = tid + i * 256;
      int r = id >> 3, c4 = id & 7;
      float4 av = *reinterpret_cast<const float4*>(&A[(size_t)(row0 + r) * K + k0 + c4 * 4]);
      float4 bv = *reinterpret_cast<const float4*>(&B[(size_t)(col0 + r) * K + k0 + c4 * 4]);
      short4v ah, bh;
      ah[0] = (short)f2bf(av.x); ah[1] = (short)f2bf(av.y);
      ah[2] = (short)f2bf(av.z); ah[3] = (short)f2bf(av.w);
      bh[0] = (short)f2bf(bv.x); bh[1] = (short)f2bf(bv.y);
      bh[2] = (short)f2bf(bv.z); bh[3] = (short)f2bf(bv.w);
      *reinterpret_cast<short4v*>(&Ah[r * 40 + c4 * 4]) = ah;
      *reinterpret_cast<short4v*>(&Bh[r * 40 + c4 * 4]) = bh;
    }
    __syncthreads();
#pragma unroll
    for (int i = 0; i < 4; i++) {
      short8v a = *reinterpret_cast<const short8v*>(&Ah[(wm * 64 + i * 16 + ln) * 40 + g * 8]);
#pragma unroll
      for (int j = 0; j < 4; j++) {
        short8v b = *reinterpret_cast<const short8v*>(&Bh[(wn * 64 + j * 16 + ln) * 40 + g * 8]);
        acc[i][j] = __builtin_amdgcn_mfma_f32_16x16x32_bf16(a, b, acc[i][j], 0, 0, 0);
      }
    }
  }
#pragma unroll
  for (int i = 0; i < 4; i++)
#pragma unroll
    for (int j = 0; j < 4; j++)
#pragma unroll
      for (int r = 0; r < 4; r++)
        C[(size_t)(row0 + wm * 64 + i * 16 + g * 4 + r) * N + col0 + wn * 64 + j * 16 + ln] =
            acc[i][j][r];
}

// ===== bf16 GEMM (A = pre-split top term Ha), transposed bf16 out =====
__global__ __launch_bounds__(256) void gemm_vbt(const short* __restrict__ Ab2,
                                                const float* __restrict__ B,
                                                ushort* __restrict__ Vt, int M, int N, int K) {
  __shared__ short Ah[128 * 40];
  __shared__ short Bh[128 * 40];
  const int tid = threadIdx.x;
  const int w = tid >> 6, l = tid & 63, g = l >> 4, ln = l & 15;
  const int wm = w >> 1, wn = w & 1;
  const int row0 = blockIdx.y * 128, col0 = blockIdx.x * 128;
  floatx4 acc[4][4] = {};
  for (int k0 = 0; k0 < K; k0 += 32) {
    __syncthreads();
#pragma unroll
    for (int i = 0; i < 2; i++) {
      int id = tid + i * 256;
      int r = id >> 2, c = id & 3;
      *reinterpret_cast<short8v*>(&Ah[r * 40 + c * 8]) =
          *reinterpret_cast<const short8v*>(&Ab2[(size_t)(row0 + r) * K + k0 + c * 8]);
    }
#pragma unroll
    for (int i = 0; i < 4; i++) {
      int id = tid + i * 256;
      int r = id >> 3, c4 = id & 7;
      float4 bv = *reinterpret_cast<const float4*>(&B[(size_t)(col0 + r) * K + k0 + c4 * 4]);
      short4v bh;
      bh[0] = (short)f2bf(bv.x); bh[1] = (short)f2bf(bv.y);
      bh[2] = (short)f2bf(bv.z); bh[3] = (short)f2bf(bv.w);
      *reinterpret_cast<short4v*>(&Bh[r * 40 + c4 * 4]) = bh;
    }
    __syncthreads();
#pragma unroll
    for (int i = 0; i < 4; i++) {
      short8v a = *reinterpret_cast<const short8v*>(&Ah[(wm * 64 + i * 16 + ln) * 40 + g * 8]);
#pragma unroll
      for (int j = 0; j < 4; j++) {
        short8v b = *reinterpret_cast<const short8v*>(&Bh[(wn * 64 + j * 16 + ln) * 40 + g * 8]);
        acc[i][j] = __builtin_amdgcn_mfma_f32_16x16x32_bf16(a, b, acc[i][j], 0, 0, 0);
      }
    }
  }
#pragma unroll
  for (int i = 0; i < 4; i++)
#pragma unroll
    for (int j = 0; j < 4; j++) {
      short4v o;
#pragma unroll
      for (int r = 0; r < 4; r++) o[r] = (short)f2bf(acc[i][j][r]);
      size_t n = col0 + wn * 64 + j * 16 + ln;
      size_t m0 = row0 + wm * 64 + i * 16 + g * 4;
      *reinterpret_cast<short4v*>(&Vt[n * M + m0]) = o;
    }
}

// ===== RoPE + 3-way split of Q,K =====
__global__ void rope_convert(const float* __restrict__ Q, const float* __restrict__ K,
                             const int* __restrict__ pos, short* __restrict__ Qa,
                             short* __restrict__ Qb, short* __restrict__ Qc,
                             short* __restrict__ Ka, short* __restrict__ Kb,
                             short* __restrict__ Kc) {
  int idx = blockIdx.x * blockDim.x + threadIdx.x;
  if (idx >= S_LEN * 64) return;
  int d = idx & 63;
  int r = idx >> 6;
  float p = (float)pos[r];
  float invf = (float)pow(10000.0, -(double)(2 * d) / 128.0);
  float ang = p * invf;
  float c = cosf(ang), s = sinf(ang);
  for (int h = 0; h < NH; h++) {
    size_t base = (size_t)r * DMODEL + h * HDIM + d;
    float q1 = Q[base], q2 = Q[base + 64];
    float k1 = K[base], k2 = K[base + 64];
    float qa = q1 * c - q2 * s, qb = q2 * c + q1 * s;
    float ka = k1 * c - k2 * s, kb = k2 * c + k1 * s;
    Split3 t;
    t = split3(qa); Qa[base] = t.a; Qb[base] = t.b; Qc[base] = t.c;
    t = split3(qb); Qa[base + 64] = t.a; Qb[base + 64] = t.b; Qc[base + 64] = t.c;
    t = split3(ka); Ka[base] = t.a; Kb[base] = t.b; Kc[base] = t.c;
    t = split3(kb); Ka[base + 64] = t.a; Kb[base + 64] = t.b; Kc[base + 64] = t.c;
  }
}

// ===== fused flash attention: grid 1024 LPT, dbuf + global_load_lds staging =====
#define KVB 32
#define KSPL (KVB * 128)  // 4096 shorts per split per buffer

__device__ __forceinline__ floatx4 qk6_tile(const short* KaS, const short* KbS,
                                            const short* KcS, const short8v q1[4],
                                            const short8v q2[4], const short8v q3[4],
                                            int krow, int g) {
  floatx4 cA = {}, cB = {}, cC = {}, cD = {}, cE = {}, cF = {};
#pragma unroll
  for (int dc = 0; dc < 4; dc++) {
    int didx = krow * 128 + ((dc * 32 + g * 8) ^ ((krow & 7) << 3));
    short8v k1 = *reinterpret_cast<const short8v*>(&KaS[didx]);
    short8v k2 = *reinterpret_cast<const short8v*>(&KbS[didx]);
    short8v k3 = *reinterpret_cast<const short8v*>(&KcS[didx]);
    cA = __builtin_amdgcn_mfma_f32_16x16x32_bf16(q1[dc], k1, cA, 0, 0, 0);
    cB = __builtin_amdgcn_mfma_f32_16x16x32_bf16(q1[dc], k2, cB, 0, 0, 0);
    cC = __builtin_amdgcn_mfma_f32_16x16x32_bf16(q2[dc], k1, cC, 0, 0, 0);
    cD = __builtin_amdgcn_mfma_f32_16x16x32_bf16(q1[dc], k3, cD, 0, 0, 0);
    cE = __builtin_amdgcn_mfma_f32_16x16x32_bf16(q2[dc], k2, cE, 0, 0, 0);
    cF = __builtin_amdgcn_mfma_f32_16x16x32_bf16(q3[dc], k1, cF, 0, 0, 0);
  }
  return ((cA + cB) + (cC + cD)) + (cE + cF);
}

// async stage: linear LDS chunks, pre-swizzled global source (inverse of read XOR)
__device__ __forceinline__ void issue_tile(const short* __restrict__ Ka,
                                           const short* __restrict__ Kb,
                                           const short* __restrict__ Kc, int k0, int h,
                                           short* bufA, short* bufB, short* bufC, int tid) {
  const int wb = tid & 192;  // wave base (uniform within wave)
#pragma unroll
  for (int it = 0; it < 2; it++) {
    int j = it * 256 + tid;  // chunk 0..511 (16B chunks)
    int r = j >> 4, cl = j & 15;
    int cg = cl ^ (r & 7);
    size_t goff = (size_t)(k0 + r) * DMODEL + h * HDIM + cg * 8;
    int cb = (it * 256 + wb) * 8;  // wave-uniform LDS base (shorts); HW adds lane*16B
    gl_lds16(Ka + goff, bufA + cb);
    gl_lds16(Kb + goff, bufB + cb);
    gl_lds16(Kc + goff, bufC + cb);
  }
}

__global__ __launch_bounds__(256, 3) void attn_fused(
    const short* __restrict__ Qa, const short* __restrict__ Qb, const short* __restrict__ Qc,
    const short* __restrict__ Ka, const short* __restrict__ Kb, const short* __restrict__ Kc,
    const ushort* __restrict__ Vt, float* __restrict__ AO, float* __restrict__ sp4) {
  __shared__ short KS[2][3][KSPL];  // 48KB double-buffered K splits
  __shared__ short Ps[4 * 512];     // 4KB per-wave P tiles
  const int bid = blockIdx.x;
  const int qb = 31 - (bid >> 5);  // LPT: biggest q-blocks dispatched first
  const int h = bid & 31;
  const int tid = threadIdx.x;
  const int w = tid >> 6, g = (tid >> 4) & 3, ln = tid & 15;
  const int q0 = qb * 64;
  const int qrow = q0 + w * 16 + ln;
  short8v q1[4], q2[4], q3[4];
#pragma unroll
  for (int dc = 0; dc < 4; dc++) {
    size_t off = (size_t)qrow * DMODEL + h * HDIM + dc * 32 + g * 8;
    q1[dc] = *reinterpret_cast<const short8v*>(&Qa[off]);
    q2[dc] = *reinterpret_cast<const short8v*>(&Qb[off]);
    q3[dc] = *reinterpret_cast<const short8v*>(&Qc[off]);
  }
  float m_r[4], l_r[4];
#pragma unroll
  for (int r = 0; r < 4; r++) { m_r[r] = NEGBIG; l_r[r] = 0.f; }
  const int nkt = 2 * qb + 2;

  // ---- pass 1: exact per-row max & sum ----
  issue_tile(Ka, Kb, Kc, 0, h, KS[0][0], KS[0][1], KS[0][2], tid);
  __syncthreads();
  for (int t = 0; t < nkt; t++) {
    const int k0 = t * KVB;
    const int cur = t & 1;
    if (t + 1 < nkt)
      issue_tile(Ka, Kb, Kc, k0 + KVB, h, KS[cur ^ 1][0], KS[cur ^ 1][1], KS[cur ^ 1][2], tid);
    float sv[2][4];
#pragma unroll
    for (int ct = 0; ct < 2; ct++) {
      floatx4 sacc = qk6_tile(KS[cur][0], KS[cur][1], KS[cur][2], q1, q2, q3, ct * 16 + ln, g);
#pragma unroll
      for (int r = 0; r < 4; r++) {
        float s = sacc[r] * ATTN_SCALE;
        int key = k0 + ct * 16 + ln;
        int qq = q0 + w * 16 + g * 4 + r;
        sv[ct][r] = (key <= qq) ? s : NEGBIG;
      }
    }
#pragma unroll
    for (int r = 0; r < 4; r++) {
      float tmax = fmaxf(sv[0][r], sv[1][r]);
      tmax = fmaxf(tmax, __shfl_xor(tmax, 1));
      tmax = fmaxf(tmax, __shfl_xor(tmax, 2));
      tmax = fmaxf(tmax, __shfl_xor(tmax, 4));
      tmax = fmaxf(tmax, __shfl_xor(tmax, 8));
      float mnew = fmaxf(m_r[r], tmax);
      float ssum = __expf(sv[0][r] - mnew) + __expf(sv[1][r] - mnew);
      ssum += __shfl_xor(ssum, 1);
      ssum += __shfl_xor(ssum, 2);
      ssum += __shfl_xor(ssum, 4);
      ssum += __shfl_xor(ssum, 8);
      l_r[r] = l_r[r] * __expf(m_r[r] - mnew) + ssum;
      m_r[r] = mnew;
    }
    __syncthreads();
  }
  float inv_l[4];
#pragma unroll
  for (int r = 0; r < 4; r++) inv_l[r] = 1.0f / l_r[r];

  // ---- pass 2: normalized p, colsums, PV ----
  floatx4 o[8] = {};
  issue_tile(Ka, Kb, Kc, 0, h, KS[0][0], KS[0][1], KS[0][2], tid);
  __syncthreads();
  for (int t = 0; t < nkt; t++) {
    const int k0 = t * KVB;
    const int cur = t & 1;
    if (t + 1 < nkt)
      issue_tile(Ka, Kb, Kc, k0 + KVB, h, KS[cur ^ 1][0], KS[cur ^ 1][1], KS[cur ^ 1][2], tid);
    float pv[2][4];
#pragma unroll
    for (int ct = 0; ct < 2; ct++) {
      floatx4 sacc = qk6_tile(KS[cur][0], KS[cur][1], KS[cur][2], q1, q2, q3, ct * 16 + ln, g);
#pragma unroll
      for (int r = 0; r < 4; r++) {
        float s = sacc[r] * ATTN_SCALE;
        int key = k0 + ct * 16 + ln;
        int qq = q0 + w * 16 + g * 4 + r;
        s = (key <= qq) ? s : NEGBIG;
        pv[ct][r] = __expf(s - m_r[r]) * inv_l[r];
      }
    }
    // per-wave column sums straight to global (deterministic)
#pragma unroll
    for (int ct = 0; ct < 2; ct++) {
      float c2 = pv[ct][0] + pv[ct][1] + pv[ct][2] + pv[ct][3];
      c2 += __shfl_xor(c2, 16);
      c2 += __shfl_xor(c2, 32);
      if (g == 0) sp4[((size_t)(qb * 4 + w) * NH + h) * S_LEN + k0 + ct * 16 + ln] = c2;
    }
    // P -> bf16 -> per-wave swizzled LDS (C-frag -> A-frag relayout)
#pragma unroll
    for (int ct = 0; ct < 2; ct++)
#pragma unroll
      for (int r = 0; r < 4; r++) {
        int prow = g * 4 + r, pcol = ct * 16 + ln;
        Ps[w * 512 + prow * 32 + (pcol ^ (((prow >> 1) & 1) << 4))] = (short)f2bf(pv[ct][r]);
      }
    short8v pa = *reinterpret_cast<const short8v*>(
        &Ps[w * 512 + ln * 32 + ((g * 8) ^ (((ln >> 1) & 1) << 4))]);
#pragma unroll
    for (int ctd = 0; ctd < 8; ctd++) {
      size_t voff = ((size_t)h * HDIM + ctd * 16 + ln) * S_LEN + k0 + g * 8;
      short8v vb = *reinterpret_cast<const short8v*>(&Vt[voff]);
      o[ctd] = __builtin_amdgcn_mfma_f32_16x16x32_bf16(pa, vb, o[ctd], 0, 0, 0);
    }
    __syncthreads();
  }
#pragma unroll
  for (int ctd = 0; ctd < 8; ctd++)
#pragma unroll
    for (int r = 0; r < 4; r++)
      AO[(size_t)(q0 + w * 16 + g * 4 + r) * DMODEL + h * HDIM + ctd * 16 + ln] = o[ctd][r];
}

// ---------------- reduce column-sum partials (128 per (h,k)) ----------------
__global__ void reduce_scores(const float* __restrict__ sp4, float* __restrict__ scores) {
  int idx = blockIdx.x * blockDim.x + threadIdx.x;
  if (idx >= NH * S_LEN) return;
  int h = idx >> 11, k = idx & 2047;
  float s = 0.f;
  for (int j = 0; j < 128; j++) s += sp4[((size_t)j * NH + h) * S_LEN + k];
  scores[idx] = s;
}

// ---------------- per-head exact top-256 + mask + previous_scores ----------------
__global__ __launch_bounds__(256) void topk_mask_kernel(const float* __restrict__ scores,
                                                        float* __restrict__ out_mask,
                                                        float* __restrict__ prev_scores) {
  const int h = blockIdx.x;
  __shared__ unsigned sb[S_LEN - RECENT];
  __shared__ int cnt_sh;
  const int NSEL = S_LEN - RECENT;
  const int tid = threadIdx.x;
  const float* sc = scores + (size_t)h * S_LEN;
  for (int i = tid; i < NSEL; i += 256) sb[i] = __float_as_uint(sc[i]);
  __syncthreads();
  unsigned prefix = 0u;
  for (int b = 31; b >= 0; b--) {
    unsigned cand = prefix | (1u << b);
    if (tid == 0) cnt_sh = 0;
    __syncthreads();
    int c = 0;
    for (int i = tid; i < NSEL; i += 256) c += (sb[i] >= cand) ? 1 : 0;
    atomicAdd(&cnt_sh, c);
    __syncthreads();
    if (cnt_sh >= HEAVY) prefix = cand;
    __syncthreads();
  }
  if (tid == 0) cnt_sh = 0;
  __syncthreads();
  int c = 0;
  for (int i = tid; i < NSEL; i += 256) c += (sb[i] > prefix) ? 1 : 0;
  atomicAdd(&cnt_sh, c);
  __syncthreads();
  const int c1 = cnt_sh;
  float* mrow = out_mask + (size_t)h * (S_LEN + 1);
  float* prow = prev_scores + (size_t)h * S_LEN;
  for (int j = NSEL + tid; j < S_LEN + 1; j += 256) mrow[j] = 1.0f;
  for (int k = NSEL + tid; k < S_LEN; k += 256) prow[k] = sc[k];
  for (int i = tid; i < NSEL; i += 256) {
    bool sel = sb[i] > prefix;
    mrow[i] = sel ? 1.f : 0.f;
    prow[i] = sel ? sc[i] : 0.f;
  }
  __syncthreads();
  if (tid == 0) {
    int need = HEAVY - c1;
    for (int i = 0; i < NSEL && need > 0; i++) {
      if (sb[i] == prefix) { mrow[i] = 1.f; prow[i] = sc[i]; need--; }
    }
  }
}

extern "C" void kernel_launch(void* const* d_in, const int* in_sizes, int n_in,
                              void* d_out, int out_size, void* d_ws, size_t ws_size,
                              hipStream_t stream) {
  const float* hidden = (const float*)d_in[0];
  const int* pos = (const int*)d_in[2];
  const float* Wq = (const float*)d_in[3];
  const float* Wk = (const float*)d_in[4];
  const float* Wv = (const float*)d_in[5];
  const float* Wo = (const float*)d_in[6];

  float* out0 = (float*)d_out;
  float* out_mask = out0 + (size_t)S_LEN * DMODEL;
  float* prev_scores = out_mask + (size_t)NH * (S_LEN + 1);

  char* ws = (char*)d_ws;
  float* Qf = (float*)(ws + 0 * MB);     // 32MB -> AO after rope
  float* Kf = (float*)(ws + 32 * MB);    // 32MB -> sp4 after rope
  ushort* Vt = (ushort*)(ws + 64 * MB);  // 16MB -> scores after attn
  // Ha/Hb/Hc live at 80/96/112MB until gemm_vbt; rope then reuses as Qa/Qb/Qc
  short* Ha = (short*)(ws + 80 * MB);
  short* Hb = (short*)(ws + 96 * MB);
  short* Hc = (short*)(ws + 112 * MB);
  short* Qa = (short*)(ws + 80 * MB);
  short* Qb = (short*)(ws + 96 * MB);
  short* Qc = (short*)(ws + 112 * MB);
  short* Ka = (short*)(ws + 128 * MB);
  short* Kb = (short*)(ws + 144 * MB);
  short* Kc = (short*)(ws + 160 * MB);  // ends at 176MB
  float* AO = Qf;
  float* sp4 = Kf;
  float* scores = (float*)(ws + 64 * MB);  // Vt dead after attn

  dim3 gg(DMODEL / 128, S_LEN / 128);
  split_mat<<<2048, 256, 0, stream>>>(hidden, Ha, Hb, Hc, S_LEN * DMODEL / 4);
  gemm6h<<<gg, 256, 0, stream>>>(Ha, Hb, Hc, Wq, Qf, S_LEN, DMODEL, DMODEL);
  gemm6h<<<gg, 256, 0, stream>>>(Ha, Hb, Hc, Wk, Kf, S_LEN, DMODEL, DMODEL);
  gemm_vbt<<<gg, 256, 0, stream>>>(Ha, Wv, Vt, S_LEN, DMODEL, DMODEL);

  int rope_total = S_LEN * 64;
  rope_convert<<<(rope_total + 255) / 256, 256, 0, stream>>>(Qf, Kf, pos, Qa, Qb, Qc, Ka, Kb, Kc);

  hipError_t _e = hipMemsetAsync(sp4, 0, (size_t)128 * NH * S_LEN * sizeof(float), stream);
  (void)_e;
  attn_fused<<<1024, 256, 0, stream>>>(Qa, Qb, Qc, Ka, Kb, Kc, Vt, AO, sp4);

  reduce_scores<<<(NH * S_LEN + 255) / 256, 256, 0, stream>>>(sp4, scores);
  topk_mask_kernel<<<NH, 256, 0, stream>>>(scores, out_mask, prev_scores);

  gemm_bf1<<<gg, 256, 0, stream>>>(AO, Wo, out0, S_LEN, DMODEL, DMODEL);
}